// Round 11
// baseline (227.346 us; speedup 1.0000x reference)
//
#include <hip/hip_runtime.h>

// ---------------------------------------------------------------------------
// MultiHeadAttention: B=4, S=2048, D=1024, H=16, dk=64
// R11: QKV GEMM ported to the 256^2 8-phase deep-pipelined schedule (T3+T4):
//      8 waves (2Mx4N), BK=64, 128KB LDS (2 K-tiles double-buffered), per
//      K-tile 4 phases of {4-8 ds_read_b128 | 2 global_load_lds staging of
//      tile T+1 | barrier | lgkmcnt(0)+sched_barrier | setprio(1) 16 MFMA
//      setprio(0) | barrier}, per-wave vmcnt(0) at group ends. Buffer parity
//      (tile t -> buf t&1) makes the overlapped staging race-free.
//      Attention / out-projection / casts / transposes unchanged from R10.
// ---------------------------------------------------------------------------

typedef _Float16 fp16;
typedef fp16  fp16x8 __attribute__((ext_vector_type(8)));
typedef fp16  fp16x4 __attribute__((ext_vector_type(4)));
typedef float f32x4  __attribute__((ext_vector_type(4)));

#define NROWS 8192     // B*S
#define DM    1024
#define SEQ   2048
#define DK    64
#define LOG2E 1.44269504088896340736f
#define QSCALE (0.125f * LOG2E)

__device__ __forceinline__ f32x4 mfma16x16(fp16x8 a, fp16x8 b, f32x4 c) {
    return __builtin_amdgcn_mfma_f32_16x16x32_f16(a, b, c, 0, 0, 0);
}

__device__ __forceinline__ void gload16(const void* g, void* l) {
    __builtin_amdgcn_global_load_lds(
        (const __attribute__((address_space(1))) void*)g,
        (__attribute__((address_space(3))) void*)l, 16, 0, 0);
}

// ---- fp32 -> fp16 cast, z-batched over 3 tensors -------------------------
__global__ __launch_bounds__(256) void cast_fp16_kernel(
    const float* __restrict__ x0, const float* __restrict__ x1,
    const float* __restrict__ x2,
    fp16* __restrict__ y0, fp16* __restrict__ y1, fp16* __restrict__ y2,
    int n4) {
    const int z = blockIdx.y;
    const float* x = (z == 0) ? x0 : (z == 1) ? x1 : x2;
    fp16*       y = (z == 0) ? y0 : (z == 1) ? y1 : y2;
    int i = blockIdx.x * 256 + threadIdx.x;
    if (i >= n4) return;
    const float4 v = ((const float4*)x)[i];
    fp16x4 o;
    o[0] = (fp16)v.x; o[1] = (fp16)v.y; o[2] = (fp16)v.z; o[3] = (fp16)v.w;
    ((fp16x4*)y)[i] = o;
}

// ---- transpose 1024x1024 fp32 W[k][n] -> fp16 T[n][k], z-batched x4 ------
__global__ __launch_bounds__(256) void transpose_w_kernel(
    const float* __restrict__ w0, const float* __restrict__ w1,
    const float* __restrict__ w2, const float* __restrict__ w3,
    fp16* __restrict__ t0, fp16* __restrict__ t1,
    fp16* __restrict__ t2, fp16* __restrict__ t3) {
    const int z = blockIdx.z;
    const float* W = (z == 0) ? w0 : (z == 1) ? w1 : (z == 2) ? w2 : w3;
    fp16*       T = (z == 0) ? t0 : (z == 1) ? t1 : (z == 2) ? t2 : t3;
    __shared__ float tile[32][33];
    const int tx = threadIdx.x, ty = threadIdx.y;
    const int bx = blockIdx.x * 32, by = blockIdx.y * 32;
#pragma unroll
    for (int j = 0; j < 4; ++j)
        tile[ty + 8 * j][tx] = W[(size_t)(by + ty + 8 * j) * DM + bx + tx];
    __syncthreads();
#pragma unroll
    for (int j = 0; j < 4; ++j)
        T[(size_t)(bx + ty + 8 * j) * DM + by + tx] = (fp16)tile[tx][ty + 8 * j];
}

// ---- QKV projection GEMM: 256x256 tile, 8-phase deep pipeline ------------
// Grid: 384 1D. Decode: XCD x = i&7 owns m-tiles [x*4, x*4+4) for all n,z.
// LDS: A/B tiles 256x64 fp16, double-buffered (tile t -> buf t&1), chunk-XOR
// swizzle (slot sl of row R holds global chunk sl^(R&7); 0 conflicts since R6).
// z 0: Q (scale, row-major out), 1: K, 2: V (V^T layout out).
__global__ __launch_bounds__(512, 2) void gemm_qkv_kernel(
    const fp16* __restrict__ Xq, const fp16* __restrict__ Xk,
    const fp16* __restrict__ Xv,
    const fp16* __restrict__ Wq, const fp16* __restrict__ Wk,
    const fp16* __restrict__ Wv,
    const float* __restrict__ bq, const float* __restrict__ bk,
    const float* __restrict__ bv,
    fp16* __restrict__ Qb, fp16* __restrict__ Kb, fp16* __restrict__ Vtg) {
    const int i = blockIdx.x;
    const int xcd = i & 7, j = i >> 3;           // j in [0,48)
    const int nt = j & 3, mloc = (j >> 2) & 3, z = j >> 4;
    const int m0 = (xcd * 4 + mloc) * 256;
    const int n0 = nt * 256;

    const fp16* __restrict__ A = (z == 0) ? Xq : (z == 1) ? Xk : Xv;
    const fp16* __restrict__ B = (z == 0) ? Wq : (z == 1) ? Wk : Wv;
    const float* __restrict__ bias = (z == 0) ? bq : (z == 1) ? bk : bv;
    fp16* __restrict__ outp = (z == 0) ? Qb : (z == 1) ? Kb : Vtg;
    const float oscale = (z == 0) ? QSCALE : 1.0f;

    const int tid = threadIdx.x;
    const int lane = tid & 63;
    const int w = tid >> 6;                      // 0..7
    const int wr = w >> 2, wc = w & 3;           // 2M x 4N waves
    const int li = lane & 15, lg = lane >> 4;
    const int srow = lane >> 3;                  // staging row-in-8
    const int sch  = (lane & 7) ^ srow;          // pre-swizzled source chunk

    __shared__ fp16 Ab[2][256 * 64];             // 64 KB
    __shared__ fp16 Bb[2][256 * 64];             // 64 KB

    f32x4 acc[8][4] = {};

    // stage issue q (0..7) of K-tile t: q<4 -> A rows (q*64..), else B rows.
    // wave w stages rows (q&3)*64 + w*8 + srow; LDS dest = wave base (+lane*16).
#define STAGE(t, q)                                                          \
    {                                                                        \
        const int rowb_ = ((q) & 3) * 64 + w * 8;                            \
        if ((q) < 4)                                                         \
            gload16(&A[(size_t)(m0 + rowb_ + srow) * DM + (t) * 64 + sch * 8],\
                    &Ab[(t) & 1][rowb_ * 64]);                               \
        else                                                                 \
            gload16(&B[(size_t)(n0 + rowb_ + srow) * DM + (t) * 64 + sch * 8],\
                    &Bb[(t) & 1][rowb_ * 64]);                               \
    }

    // prologue: stage tile 0 into buf0, drain, publish
#pragma unroll
    for (int q = 0; q < 8; ++q) STAGE(0, q);
    asm volatile("s_waitcnt vmcnt(0)" ::: "memory");
    __syncthreads();

    for (int it = 0; it < 8; ++it) {
#pragma unroll
        for (int grp = 0; grp < 2; ++grp) {
            const int T = it * 2 + grp;          // tile computed (buf T&1)
            const int g = T & 1;
            const int S = T + 1;                 // tile staged (buf g^1)
            fp16x8 bfr[4];
#pragma unroll
            for (int p = 0; p < 4; ++p) {
                const int ks = p >> 1, mh = p & 1;
                // ds-load register subtiles (4 or 8 x ds_read_b128)
                fp16x8 af[4];
#pragma unroll
                for (int m4 = 0; m4 < 4; ++m4) {
                    int mf = mh * 4 + m4;
                    af[m4] = *(const fp16x8*)&Ab[g][(wr * 128 + mf * 16 + li) * 64 +
                                                    (((ks * 4 + lg) ^ (li & 7)) * 8)];
                }
                if (mh == 0) {
#pragma unroll
                    for (int nf = 0; nf < 4; ++nf)
                        bfr[nf] = *(const fp16x8*)&Bb[g][(wc * 64 + nf * 16 + li) * 64 +
                                                         (((ks * 4 + lg) ^ (li & 7)) * 8)];
                }
                // stage 2 issues of tile S (other buffer; race-free by parity)
                if (S < 16) { STAGE(S, p * 2); STAGE(S, p * 2 + 1); }
                __builtin_amdgcn_s_barrier();
                asm volatile("s_waitcnt lgkmcnt(0)" ::: "memory");
                __builtin_amdgcn_sched_barrier(0);
                __builtin_amdgcn_s_setprio(1);
#pragma unroll
                for (int m4 = 0; m4 < 4; ++m4)
#pragma unroll
                    for (int nf = 0; nf < 4; ++nf)
                        acc[mh * 4 + m4][nf] =
                            mfma16x16(af[m4], bfr[nf], acc[mh * 4 + m4][nf]);
                __builtin_amdgcn_s_setprio(0);
                if (p == 3)   // group end: each wave drains its DMA, then publish
                    asm volatile("s_waitcnt vmcnt(0)" ::: "memory");
                __builtin_amdgcn_s_barrier();
            }
        }
    }
#undef STAGE

#pragma unroll
    for (int nf = 0; nf < 4; ++nf) {
        int col = n0 + wc * 64 + nf * 16 + li;
        float bv_ = bias[col];
        if (z == 2) {           // V^T layout [b*1024 + col][s]
#pragma unroll
            for (int mf = 0; mf < 8; ++mf) {
                int rowb = m0 + wr * 128 + mf * 16 + lg * 4;
                fp16x4 pk;
#pragma unroll
                for (int r2 = 0; r2 < 4; ++r2)
                    pk[r2] = (fp16)(acc[mf][nf][r2] + bv_);
                size_t o = ((size_t)(rowb >> 11) * 1024 + col) * SEQ + (rowb & 2047);
                *(fp16x4*)&outp[o] = pk;
            }
        } else {
#pragma unroll
            for (int mf = 0; mf < 8; ++mf)
#pragma unroll
                for (int r2 = 0; r2 < 4; ++r2) {
                    int row = m0 + wr * 128 + mf * 16 + lg * 4 + r2;
                    outp[(size_t)row * DM + col] = (fp16)((acc[mf][nf][r2] + bv_) * oscale);
                }
        }
    }
}

// ---- Out-projection GEMM: fp16 A/B, 128x64 tile, XCD-aware decode --------
__global__ __launch_bounds__(256) void gemm_out_kernel(
    const fp16* __restrict__ A, const fp16* __restrict__ B,
    const float* __restrict__ bias, float* __restrict__ outp) {
    const int i = blockIdx.x;
    const int xcd = i & 7, r = i >> 3;           // r in [0,128)
    const int m0 = (xcd * 8 + (r >> 4)) * 128;
    const int n0 = (r & 15) * 64;

    const int tid = threadIdx.x;
    const int lane = tid & 63;
    const int w = tid >> 6;
    const int wr = w >> 1, wc = w & 1;
    const int li = lane & 15, lg = lane >> 4;
    const int lrow = lane >> 3;
    const int lch  = (lane & 7) ^ lrow;

    __shared__ fp16 At[128 * 64];
    __shared__ fp16 Bt[64 * 64];

    f32x4 acc[4][2] = {};

    for (int k0 = 0; k0 < DM; k0 += 64) {
        __syncthreads();
#pragma unroll
        for (int it = 0; it < 4; ++it) {
            int R = (w * 4 + it) * 8 + lrow;
            gload16(&A[(size_t)(m0 + R) * DM + k0 + lch * 8], &At[(w * 4 + it) * 512]);
            if (it < 2) {
                int Rb = (w * 2 + it) * 8 + lrow;
                gload16(&B[(size_t)(n0 + Rb) * DM + k0 + lch * 8], &Bt[(w * 2 + it) * 512]);
            }
        }
        __syncthreads();
        fp16x8 af[4][2], bfr[2][2];
#pragma unroll
        for (int mf = 0; mf < 4; ++mf)
#pragma unroll
            for (int ks = 0; ks < 2; ++ks)
                af[mf][ks] = *(const fp16x8*)&At[(wr * 64 + mf * 16 + li) * 64 +
                                                 (((ks * 4 + lg) ^ (li & 7)) * 8)];
#pragma unroll
        for (int nf = 0; nf < 2; ++nf)
#pragma unroll
            for (int ks = 0; ks < 2; ++ks)
                bfr[nf][ks] = *(const fp16x8*)&Bt[(wc * 32 + nf * 16 + li) * 64 +
                                                  (((ks * 4 + lg) ^ (li & 7)) * 8)];
#pragma unroll
        for (int ks = 0; ks < 2; ++ks)
#pragma unroll
            for (int mf = 0; mf < 4; ++mf)
#pragma unroll
                for (int nf = 0; nf < 2; ++nf)
                    acc[mf][nf] = mfma16x16(af[mf][ks], bfr[nf][ks], acc[mf][nf]);
    }
#pragma unroll
    for (int nf = 0; nf < 2; ++nf) {
        int col = n0 + wc * 32 + nf * 16 + li;
        float bv_ = bias[col];
#pragma unroll
        for (int mf = 0; mf < 4; ++mf)
#pragma unroll
            for (int r2 = 0; r2 < 4; ++r2) {
                int row = m0 + wr * 64 + mf * 16 + lg * 4 + r2;
                outp[(size_t)row * DM + col] = acc[mf][nf][r2] + bv_;
            }
    }
}

// ---- Flash attention: swapped QK^T, 8 waves, no-max softmax, K/V LDS dbuf,
//      ONE barrier per KV tile (loads issued a full compute phase early).
__global__ __launch_bounds__(512) void attn_kernel(
    const fp16* __restrict__ Qb, const fp16* __restrict__ Kb,
    const fp16* __restrict__ Vtg, fp16* __restrict__ Of) {
    const int tid = threadIdx.x;
    const int lane = tid & 63;
    const int w = tid >> 6;                  // 0..7
    const int li = lane & 15, lg = lane >> 4;

    int L = blockIdx.x;
    L = (L & 7) * 64 + (L >> 3);             // bijective XCD swizzle (512 = 8*64)
    const int qt = L & 7, bh = L >> 3;
    const int b = bh >> 4, h = bh & 15;
    const size_t rowQ = (size_t)b * SEQ + (size_t)qt * 256;
    const int c0 = h * DK;

    __shared__ fp16 Kt[2][64 * 64];     // [kv][d], chunk-swizzled
    __shared__ fp16 Vt[2][64 * 64];     // [d][kv], chunk-swizzled
    __shared__ fp16 Pl[8][32 * 64];     // per-wave P [q][kv], chunk-swizzled

    fp16x8 qf[2][2];
#pragma unroll
    for (int mf = 0; mf < 2; ++mf)
#pragma unroll
        for (int ks = 0; ks < 2; ++ks)
            qf[mf][ks] = *(const fp16x8*)&Qb[(rowQ + w * 32 + mf * 16 + li) * DM +
                                             c0 + ks * 32 + lg * 8];

    fp16x8 ones;
#pragma unroll
    for (int j = 0; j < 8; ++j) ones[j] = (fp16)1.0f;

    f32x4 oacc[2][4] = {};
    f32x4 lacc[2] = {};

    const int sr = tid >> 3, sc = tid & 7;
    const int ssl = sc ^ (sr & 7);
    fp16x8 rk, rv;
    rk = *(const fp16x8*)&Kb[((size_t)b * SEQ + sr) * DM + c0 + sc * 8];
    rv = *(const fp16x8*)&Vtg[((size_t)bh * 64 + sr) * SEQ + sc * 8];
    *(fp16x8*)&Kt[0][sr * 64 + ssl * 8] = rk;
    *(fp16x8*)&Vt[0][sr * 64 + ssl * 8] = rv;
    __syncthreads();

    for (int kt = 0; kt < SEQ / 64; ++kt) {
        const int cur = kt & 1;
        const bool more = (kt + 1 < SEQ / 64);
        if (more) {                      // loads overlap the whole compute phase
            rk = *(const fp16x8*)&Kb[((size_t)b * SEQ + (kt + 1) * 64 + sr) * DM + c0 + sc * 8];
            rv = *(const fp16x8*)&Vtg[((size_t)bh * 64 + sr) * SEQ + (kt + 1) * 64 + sc * 8];
        }

        // S^T = K Q^T : lane holds q=li, kv=nf*16+lg*4+r
        f32x4 s[4][2] = {};
        __builtin_amdgcn_s_setprio(1);
#pragma unroll
        for (int nf = 0; nf < 4; ++nf)
#pragma unroll
            for (int ks = 0; ks < 2; ++ks) {
                fp16x8 kf = *(const fp16x8*)&Kt[cur][(nf * 16 + li) * 64 +
                                                     (((ks * 4 + lg) ^ (li & 7)) * 8)];
#pragma unroll
                for (int mf = 0; mf < 2; ++mf)
                    s[nf][mf] = mfma16x16(kf, qf[mf][ks], s[nf][mf]);
            }
        __builtin_amdgcn_s_setprio(0);

        // p = exp2(s) -> per-wave LDS (vectorized, swizzled)
#pragma unroll
        for (int mf = 0; mf < 2; ++mf) {
            fp16x4 pk[4];
#pragma unroll
            for (int nf = 0; nf < 4; ++nf)
#pragma unroll
                for (int r = 0; r < 4; ++r)
                    pk[nf][r] = (fp16)__builtin_amdgcn_exp2f(s[nf][mf][r]);
            int row = mf * 16 + li;
#pragma unroll
            for (int nf = 0; nf < 4; ++nf) {
                int sl = (nf * 2 + (lg >> 1)) ^ (li & 7);
                *(fp16x4*)&Pl[w][row * 64 + sl * 8 + (lg & 1) * 4] = pk[nf];
            }
        }

        // O += P V ; l += P 1
        __builtin_amdgcn_s_setprio(1);
#pragma unroll
        for (int ks = 0; ks < 2; ++ks) {
            fp16x8 pf[2];
#pragma unroll
            for (int mf = 0; mf < 2; ++mf) {
                pf[mf] = *(const fp16x8*)&Pl[w][(mf * 16 + li) * 64 +
                                                (((ks * 4 + lg) ^ (li & 7)) * 8)];
                lacc[mf] = mfma16x16(pf[mf], ones, lacc[mf]);
            }
#pragma unroll
            for (int nf = 0; nf < 4; ++nf) {
                fp16x8 vf = *(const fp16x8*)&Vt[cur][(nf * 16 + li) * 64 +
                                                     (((ks * 4 + lg) ^ (li & 7)) * 8)];
#pragma unroll
                for (int mf = 0; mf < 2; ++mf)
                    oacc[mf][nf] = mfma16x16(pf[mf], vf, oacc[mf][nf]);
            }
        }
        __builtin_amdgcn_s_setprio(0);

        if (more) {                      // stage tile kt+1 into the other buffer
            *(fp16x8*)&Kt[cur ^ 1][sr * 64 + ssl * 8] = rk;
            *(fp16x8*)&Vt[cur ^ 1][sr * 64 + ssl * 8] = rv;
            __syncthreads();             // one barrier per tile
        }
    }

    // epilogue: O /= l (lacc in oacc row layout), write fp16
#pragma unroll
    for (int mf = 0; mf < 2; ++mf) {
#pragma unroll
        for (int r = 0; r < 4; ++r) {
            float linv = 1.0f / lacc[mf][r];
            size_t row = rowQ + w * 32 + mf * 16 + lg * 4 + r;
#pragma unroll
            for (int nf = 0; nf < 4; ++nf) {
                int col = c0 + nf * 16 + li;
                Of[row * DM + col] = (fp16)(oacc[mf][nf][r] * linv);
            }
        }
    }
}

// ---------------------------------------------------------------------------
extern "C" void kernel_launch(void* const* d_in, const int* in_sizes, int n_in,
                              void* d_out, int out_size, void* d_ws, size_t ws_size,
                              hipStream_t stream) {
    const float* query = (const float*)d_in[0];
    const float* key   = (const float*)d_in[1];
    const float* value = (const float*)d_in[2];
    const float* wq    = (const float*)d_in[3];
    const float* bq    = (const float*)d_in[4];
    const float* wk    = (const float*)d_in[5];
    const float* bk    = (const float*)d_in[6];
    const float* wv    = (const float*)d_in[7];
    const float* bv    = (const float*)d_in[8];
    const float* wo    = (const float*)d_in[9];
    const float* bo    = (const float*)d_in[10];

    char* ws = (char*)d_ws;
    const size_t SZX = (size_t)NROWS * DM * 2;   // 16 MB (fp16)
    const size_t SZW = (size_t)DM * DM * 2;      //  2 MB (fp16)
    fp16* Xq  = (fp16*)(ws);
    fp16* Xk  = (fp16*)(ws + SZX);
    fp16* Xv  = (fp16*)(ws + 2 * SZX);
    fp16* Wtq = (fp16*)(ws + 3 * SZX);
    fp16* Wtk = (fp16*)(ws + 3 * SZX + SZW);
    fp16* Wtv = (fp16*)(ws + 3 * SZX + 2 * SZW);
    fp16* Wto = (fp16*)(ws + 3 * SZX + 3 * SZW);
    fp16* Qb  = (fp16*)(ws + 3 * SZX + 4 * SZW);
    fp16* Kb  = (fp16*)(ws + 4 * SZX + 4 * SZW);
    fp16* Vtg = (fp16*)(ws + 5 * SZX + 4 * SZW); // V^T [b*1024+h*64+d][s]
    fp16* Of  = Xq;                              // Xq dead after QKV GEMMs

    const int n4 = NROWS * DM / 4;
    const dim3 bT(32, 8);

    cast_fp16_kernel<<<dim3(8192, 3), 256, 0, stream>>>(
        query, key, value, Xq, Xk, Xv, n4);
    transpose_w_kernel<<<dim3(32, 32, 4), bT, 0, stream>>>(
        wq, wk, wv, wo, Wtq, Wtk, Wtv, Wto);
    gemm_qkv_kernel<<<384, 512, 0, stream>>>(
        Xq, Xk, Xv, Wtq, Wtk, Wtv, bq, bk, bv, Qb, Kb, Vtg);
    attn_kernel<<<512, 512, 0, stream>>>(Qb, Kb, Vtg, Of);
    gemm_out_kernel<<<1024, 256, 0, stream>>>(Of, Wto, bo, (float*)d_out);
}

// Round 12
// 211.810 us; speedup vs baseline: 1.0733x; 1.0733x over previous
//
#include <hip/hip_runtime.h>

// ---------------------------------------------------------------------------
// MultiHeadAttention: B=4, S=2048, D=1024, H=16, dk=64
// R12: revert QKV to R10's measured-best structure (fp16 A/B dual
//      global_load_lds, 2 barriers/step, 5 blocks/CU, XCD-aware decode).
//      R11's 8-phase (1 block/CU + grid tail + over-drained vmcnt) abandoned.
//      One micro-fix: attention P-pack via v_cvt_pkrtz (halves cvt VALU ops
//      on the busier pipe). Everything else unchanged.
// ---------------------------------------------------------------------------

typedef _Float16 fp16;
typedef fp16  fp16x8 __attribute__((ext_vector_type(8)));
typedef fp16  fp16x4 __attribute__((ext_vector_type(4)));
typedef __fp16 h16x2 __attribute__((ext_vector_type(2)));
typedef float f32x4  __attribute__((ext_vector_type(4)));

#define NROWS 8192     // B*S
#define DM    1024
#define SEQ   2048
#define DK    64
#define LOG2E 1.44269504088896340736f
#define QSCALE (0.125f * LOG2E)

__device__ __forceinline__ f32x4 mfma16x16(fp16x8 a, fp16x8 b, f32x4 c) {
    return __builtin_amdgcn_mfma_f32_16x16x32_f16(a, b, c, 0, 0, 0);
}

__device__ __forceinline__ void gload16(const void* g, void* l) {
    __builtin_amdgcn_global_load_lds(
        (const __attribute__((address_space(1))) void*)g,
        (__attribute__((address_space(3))) void*)l, 16, 0, 0);
}

// pack 4 f32 -> fp16x4 with v_cvt_pkrtz (2 instructions)
__device__ __forceinline__ fp16x4 pack4(float a, float b, float c, float d) {
    h16x2 r0 = __builtin_amdgcn_cvt_pkrtz(a, b);
    h16x2 r1 = __builtin_amdgcn_cvt_pkrtz(c, d);
    fp16x4 v;
    v[0] = (fp16)r0[0]; v[1] = (fp16)r0[1];
    v[2] = (fp16)r1[0]; v[3] = (fp16)r1[1];
    return v;
}

// ---- fp32 -> fp16 cast, z-batched over 3 tensors -------------------------
__global__ __launch_bounds__(256) void cast_fp16_kernel(
    const float* __restrict__ x0, const float* __restrict__ x1,
    const float* __restrict__ x2,
    fp16* __restrict__ y0, fp16* __restrict__ y1, fp16* __restrict__ y2,
    int n4) {
    const int z = blockIdx.y;
    const float* x = (z == 0) ? x0 : (z == 1) ? x1 : x2;
    fp16*       y = (z == 0) ? y0 : (z == 1) ? y1 : y2;
    int i = blockIdx.x * 256 + threadIdx.x;
    if (i >= n4) return;
    const float4 v = ((const float4*)x)[i];
    ((fp16x4*)y)[i] = pack4(v.x, v.y, v.z, v.w);
}

// ---- transpose 1024x1024 fp32 W[k][n] -> fp16 T[n][k], z-batched x4 ------
__global__ __launch_bounds__(256) void transpose_w_kernel(
    const float* __restrict__ w0, const float* __restrict__ w1,
    const float* __restrict__ w2, const float* __restrict__ w3,
    fp16* __restrict__ t0, fp16* __restrict__ t1,
    fp16* __restrict__ t2, fp16* __restrict__ t3) {
    const int z = blockIdx.z;
    const float* W = (z == 0) ? w0 : (z == 1) ? w1 : (z == 2) ? w2 : w3;
    fp16*       T = (z == 0) ? t0 : (z == 1) ? t1 : (z == 2) ? t2 : t3;
    __shared__ float tile[32][33];
    const int tx = threadIdx.x, ty = threadIdx.y;
    const int bx = blockIdx.x * 32, by = blockIdx.y * 32;
#pragma unroll
    for (int j = 0; j < 4; ++j)
        tile[ty + 8 * j][tx] = W[(size_t)(by + ty + 8 * j) * DM + bx + tx];
    __syncthreads();
#pragma unroll
    for (int j = 0; j < 4; ++j)
        T[(size_t)(bx + ty + 8 * j) * DM + by + tx] = (fp16)tile[tx][ty + 8 * j];
}

// ---- QKV projection GEMM: fp16 A and B via dual global_load_lds ----------
// Grid: 1536 1D. Decode: XCD x = i&7 owns m-slabs [x*8, x*8+8) for all n,z
// (A-panels L2-resident per XCD). 2 barriers per K-step, ~5 blocks/CU TLP.
// z 0: Q (scale, row-major out), 1: K, 2: V (V^T layout out).
__global__ __launch_bounds__(256) void gemm_qkv_kernel(
    const fp16* __restrict__ Xq, const fp16* __restrict__ Xk,
    const fp16* __restrict__ Xv,
    const fp16* __restrict__ Wq, const fp16* __restrict__ Wk,
    const fp16* __restrict__ Wv,
    const float* __restrict__ bq, const float* __restrict__ bk,
    const float* __restrict__ bv,
    fp16* __restrict__ Qb, fp16* __restrict__ Kb, fp16* __restrict__ Vtg) {
    const int i = blockIdx.x;
    const int xcd = i & 7, r = i >> 3;           // r in [0,192)
    const int z = r >> 6, rr = r & 63;
    const int m0 = (xcd * 8 + (rr >> 3)) * 128;  // m-slab, XCD-local
    const int n0 = (rr & 7) * 128;

    const fp16* __restrict__ A = (z == 0) ? Xq : (z == 1) ? Xk : Xv;
    const fp16* __restrict__ B = (z == 0) ? Wq : (z == 1) ? Wk : Wv;
    const float* __restrict__ bias = (z == 0) ? bq : (z == 1) ? bk : bv;
    fp16* __restrict__ outp = (z == 0) ? Qb : (z == 1) ? Kb : Vtg;
    const float oscale = (z == 0) ? QSCALE : 1.0f;

    const int tid = threadIdx.x;
    const int lane = tid & 63;
    const int w = tid >> 6;
    const int wr = w >> 1, wc = w & 1;
    const int li = lane & 15, lg = lane >> 4;
    const int lrow = lane >> 3;
    const int lch  = (lane & 7) ^ lrow;          // pre-swizzled source chunk

    __shared__ fp16 At[128 * 64];
    __shared__ fp16 Bt[128 * 64];

    f32x4 acc[4][4] = {};

    for (int k0 = 0; k0 < DM; k0 += 64) {
        __syncthreads();
#pragma unroll
        for (int it = 0; it < 4; ++it) {
            int R = (w * 4 + it) * 8 + lrow;
            gload16(&A[(size_t)(m0 + R) * DM + k0 + lch * 8], &At[(w * 4 + it) * 512]);
            gload16(&B[(size_t)(n0 + R) * DM + k0 + lch * 8], &Bt[(w * 4 + it) * 512]);
        }
        __syncthreads();
        fp16x8 af[4][2], bfr[4][2];
#pragma unroll
        for (int mf = 0; mf < 4; ++mf)
#pragma unroll
            for (int ks = 0; ks < 2; ++ks)
                af[mf][ks] = *(const fp16x8*)&At[(wr * 64 + mf * 16 + li) * 64 +
                                                 (((ks * 4 + lg) ^ (li & 7)) * 8)];
#pragma unroll
        for (int nf = 0; nf < 4; ++nf)
#pragma unroll
            for (int ks = 0; ks < 2; ++ks)
                bfr[nf][ks] = *(const fp16x8*)&Bt[(wc * 64 + nf * 16 + li) * 64 +
                                                  (((ks * 4 + lg) ^ (li & 7)) * 8)];
#pragma unroll
        for (int ks = 0; ks < 2; ++ks)
#pragma unroll
            for (int mf = 0; mf < 4; ++mf)
#pragma unroll
                for (int nf = 0; nf < 4; ++nf)
                    acc[mf][nf] = mfma16x16(af[mf][ks], bfr[nf][ks], acc[mf][nf]);
    }
#pragma unroll
    for (int nf = 0; nf < 4; ++nf) {
        int col = n0 + wc * 64 + nf * 16 + li;
        float bv_ = bias[col];
        if (z == 2) {           // V^T layout [b*1024 + col][s]
#pragma unroll
            for (int mf = 0; mf < 4; ++mf) {
                int rowb = m0 + wr * 64 + mf * 16 + lg * 4;
                fp16x4 pk;
#pragma unroll
                for (int r2 = 0; r2 < 4; ++r2)
                    pk[r2] = (fp16)(acc[mf][nf][r2] + bv_);
                size_t o = ((size_t)(rowb >> 11) * 1024 + col) * SEQ + (rowb & 2047);
                *(fp16x4*)&outp[o] = pk;
            }
        } else {
#pragma unroll
            for (int mf = 0; mf < 4; ++mf)
#pragma unroll
                for (int r2 = 0; r2 < 4; ++r2) {
                    int row = m0 + wr * 64 + mf * 16 + lg * 4 + r2;
                    outp[(size_t)row * DM + col] = (fp16)((acc[mf][nf][r2] + bv_) * oscale);
                }
        }
    }
}

// ---- Out-projection GEMM: fp16 A/B, 128x64 tile, XCD-aware decode --------
__global__ __launch_bounds__(256) void gemm_out_kernel(
    const fp16* __restrict__ A, const fp16* __restrict__ B,
    const float* __restrict__ bias, float* __restrict__ outp) {
    const int i = blockIdx.x;
    const int xcd = i & 7, r = i >> 3;           // r in [0,128)
    const int m0 = (xcd * 8 + (r >> 4)) * 128;
    const int n0 = (r & 15) * 64;

    const int tid = threadIdx.x;
    const int lane = tid & 63;
    const int w = tid >> 6;
    const int wr = w >> 1, wc = w & 1;
    const int li = lane & 15, lg = lane >> 4;
    const int lrow = lane >> 3;
    const int lch  = (lane & 7) ^ lrow;

    __shared__ fp16 At[128 * 64];
    __shared__ fp16 Bt[64 * 64];

    f32x4 acc[4][2] = {};

    for (int k0 = 0; k0 < DM; k0 += 64) {
        __syncthreads();
#pragma unroll
        for (int it = 0; it < 4; ++it) {
            int R = (w * 4 + it) * 8 + lrow;
            gload16(&A[(size_t)(m0 + R) * DM + k0 + lch * 8], &At[(w * 4 + it) * 512]);
            if (it < 2) {
                int Rb = (w * 2 + it) * 8 + lrow;
                gload16(&B[(size_t)(n0 + Rb) * DM + k0 + lch * 8], &Bt[(w * 2 + it) * 512]);
            }
        }
        __syncthreads();
        fp16x8 af[4][2], bfr[2][2];
#pragma unroll
        for (int mf = 0; mf < 4; ++mf)
#pragma unroll
            for (int ks = 0; ks < 2; ++ks)
                af[mf][ks] = *(const fp16x8*)&At[(wr * 64 + mf * 16 + li) * 64 +
                                                 (((ks * 4 + lg) ^ (li & 7)) * 8)];
#pragma unroll
        for (int nf = 0; nf < 2; ++nf)
#pragma unroll
            for (int ks = 0; ks < 2; ++ks)
                bfr[nf][ks] = *(const fp16x8*)&Bt[(wc * 32 + nf * 16 + li) * 64 +
                                                  (((ks * 4 + lg) ^ (li & 7)) * 8)];
#pragma unroll
        for (int ks = 0; ks < 2; ++ks)
#pragma unroll
            for (int mf = 0; mf < 4; ++mf)
#pragma unroll
                for (int nf = 0; nf < 2; ++nf)
                    acc[mf][nf] = mfma16x16(af[mf][ks], bfr[nf][ks], acc[mf][nf]);
    }
#pragma unroll
    for (int nf = 0; nf < 2; ++nf) {
        int col = n0 + wc * 32 + nf * 16 + li;
        float bv_ = bias[col];
#pragma unroll
        for (int mf = 0; mf < 4; ++mf)
#pragma unroll
            for (int r2 = 0; r2 < 4; ++r2) {
                int row = m0 + wr * 64 + mf * 16 + lg * 4 + r2;
                outp[(size_t)row * DM + col] = acc[mf][nf][r2] + bv_;
            }
    }
}

// ---- Flash attention: swapped QK^T, 8 waves, no-max softmax, K/V LDS dbuf,
//      ONE barrier per KV tile (loads issued a full compute phase early).
__global__ __launch_bounds__(512) void attn_kernel(
    const fp16* __restrict__ Qb, const fp16* __restrict__ Kb,
    const fp16* __restrict__ Vtg, fp16* __restrict__ Of) {
    const int tid = threadIdx.x;
    const int lane = tid & 63;
    const int w = tid >> 6;                  // 0..7
    const int li = lane & 15, lg = lane >> 4;

    int L = blockIdx.x;
    L = (L & 7) * 64 + (L >> 3);             // bijective XCD swizzle (512 = 8*64)
    const int qt = L & 7, bh = L >> 3;
    const int b = bh >> 4, h = bh & 15;
    const size_t rowQ = (size_t)b * SEQ + (size_t)qt * 256;
    const int c0 = h * DK;

    __shared__ fp16 Kt[2][64 * 64];     // [kv][d], chunk-swizzled
    __shared__ fp16 Vt[2][64 * 64];     // [d][kv], chunk-swizzled
    __shared__ fp16 Pl[8][32 * 64];     // per-wave P [q][kv], chunk-swizzled

    fp16x8 qf[2][2];
#pragma unroll
    for (int mf = 0; mf < 2; ++mf)
#pragma unroll
        for (int ks = 0; ks < 2; ++ks)
            qf[mf][ks] = *(const fp16x8*)&Qb[(rowQ + w * 32 + mf * 16 + li) * DM +
                                             c0 + ks * 32 + lg * 8];

    fp16x8 ones;
#pragma unroll
    for (int j = 0; j < 8; ++j) ones[j] = (fp16)1.0f;

    f32x4 oacc[2][4] = {};
    f32x4 lacc[2] = {};

    const int sr = tid >> 3, sc = tid & 7;
    const int ssl = sc ^ (sr & 7);
    fp16x8 rk, rv;
    rk = *(const fp16x8*)&Kb[((size_t)b * SEQ + sr) * DM + c0 + sc * 8];
    rv = *(const fp16x8*)&Vtg[((size_t)bh * 64 + sr) * SEQ + sc * 8];
    *(fp16x8*)&Kt[0][sr * 64 + ssl * 8] = rk;
    *(fp16x8*)&Vt[0][sr * 64 + ssl * 8] = rv;
    __syncthreads();

    for (int kt = 0; kt < SEQ / 64; ++kt) {
        const int cur = kt & 1;
        const bool more = (kt + 1 < SEQ / 64);
        if (more) {                      // loads overlap the whole compute phase
            rk = *(const fp16x8*)&Kb[((size_t)b * SEQ + (kt + 1) * 64 + sr) * DM + c0 + sc * 8];
            rv = *(const fp16x8*)&Vtg[((size_t)bh * 64 + sr) * SEQ + (kt + 1) * 64 + sc * 8];
        }

        // S^T = K Q^T : lane holds q=li, kv=nf*16+lg*4+r
        f32x4 s[4][2] = {};
        __builtin_amdgcn_s_setprio(1);
#pragma unroll
        for (int nf = 0; nf < 4; ++nf)
#pragma unroll
            for (int ks = 0; ks < 2; ++ks) {
                fp16x8 kf = *(const fp16x8*)&Kt[cur][(nf * 16 + li) * 64 +
                                                     (((ks * 4 + lg) ^ (li & 7)) * 8)];
#pragma unroll
                for (int mf = 0; mf < 2; ++mf)
                    s[nf][mf] = mfma16x16(kf, qf[mf][ks], s[nf][mf]);
            }
        __builtin_amdgcn_s_setprio(0);

        // p = exp2(s) -> per-wave LDS (pkrtz pack, swizzled)
#pragma unroll
        for (int mf = 0; mf < 2; ++mf) {
            int row = mf * 16 + li;
#pragma unroll
            for (int nf = 0; nf < 4; ++nf) {
                fp16x4 pk = pack4(
                    __builtin_amdgcn_exp2f(s[nf][mf][0]),
                    __builtin_amdgcn_exp2f(s[nf][mf][1]),
                    __builtin_amdgcn_exp2f(s[nf][mf][2]),
                    __builtin_amdgcn_exp2f(s[nf][mf][3]));
                int sl = (nf * 2 + (lg >> 1)) ^ (li & 7);
                *(fp16x4*)&Pl[w][row * 64 + sl * 8 + (lg & 1) * 4] = pk;
            }
        }

        // O += P V ; l += P 1
        __builtin_amdgcn_s_setprio(1);
#pragma unroll
        for (int ks = 0; ks < 2; ++ks) {
            fp16x8 pf[2];
#pragma unroll
            for (int mf = 0; mf < 2; ++mf) {
                pf[mf] = *(const fp16x8*)&Pl[w][(mf * 16 + li) * 64 +
                                                (((ks * 4 + lg) ^ (li & 7)) * 8)];
                lacc[mf] = mfma16x16(pf[mf], ones, lacc[mf]);
            }
#pragma unroll
            for (int nf = 0; nf < 4; ++nf) {
                fp16x8 vf = *(const fp16x8*)&Vt[cur][(nf * 16 + li) * 64 +
                                                     (((ks * 4 + lg) ^ (li & 7)) * 8)];
#pragma unroll
                for (int mf = 0; mf < 2; ++mf)
                    oacc[mf][nf] = mfma16x16(pf[mf], vf, oacc[mf][nf]);
            }
        }
        __builtin_amdgcn_s_setprio(0);

        if (more) {                      // stage tile kt+1 into the other buffer
            *(fp16x8*)&Kt[cur ^ 1][sr * 64 + ssl * 8] = rk;
            *(fp16x8*)&Vt[cur ^ 1][sr * 64 + ssl * 8] = rv;
            __syncthreads();             // one barrier per tile
        }
    }

    // epilogue: O /= l (lacc in oacc row layout), write fp16
#pragma unroll
    for (int mf = 0; mf < 2; ++mf) {
#pragma unroll
        for (int r = 0; r < 4; ++r) {
            float linv = 1.0f / lacc[mf][r];
            size_t row = rowQ + w * 32 + mf * 16 + lg * 4 + r;
#pragma unroll
            for (int nf = 0; nf < 4; ++nf) {
                int col = c0 + nf * 16 + li;
                Of[row * DM + col] = (fp16)(oacc[mf][nf][r] * linv);
            }
        }
    }
}

// ---------------------------------------------------------------------------
extern "C" void kernel_launch(void* const* d_in, const int* in_sizes, int n_in,
                              void* d_out, int out_size, void* d_ws, size_t ws_size,
                              hipStream_t stream) {
    const float* query = (const float*)d_in[0];
    const float* key   = (const float*)d_in[1];
    const float* value = (const float*)d_in[2];
    const float* wq    = (const float*)d_in[3];
    const float* bq    = (const float*)d_in[4];
    const float* wk    = (const float*)d_in[5];
    const float* bk    = (const float*)d_in[6];
    const float* wv    = (const float*)d_in[7];
    const float* bv    = (const float*)d_in[8];
    const float* wo    = (const float*)d_in[9];
    const float* bo    = (const float*)d_in[10];

    char* ws = (char*)d_ws;
    const size_t SZX = (size_t)NROWS * DM * 2;   // 16 MB (fp16)
    const size_t SZW = (size_t)DM * DM * 2;      //  2 MB (fp16)
    fp16* Xq  = (fp16*)(ws);
    fp16* Xk  = (fp16*)(ws + SZX);
    fp16* Xv  = (fp16*)(ws + 2 * SZX);
    fp16* Wtq = (fp16*)(ws + 3 * SZX);
    fp16* Wtk = (fp16*)(ws + 3 * SZX + SZW);
    fp16* Wtv = (fp16*)(ws + 3 * SZX + 2 * SZW);
    fp16* Wto = (fp16*)(ws + 3 * SZX + 3 * SZW);
    fp16* Qb  = (fp16*)(ws + 3 * SZX + 4 * SZW);
    fp16* Kb  = (fp16*)(ws + 4 * SZX + 4 * SZW);
    fp16* Vtg = (fp16*)(ws + 5 * SZX + 4 * SZW); // V^T [b*1024+h*64+d][s]
    fp16* Of  = Xq;                              // Xq dead after QKV GEMMs

    const int n4 = NROWS * DM / 4;
    const dim3 bT(32, 8);

    cast_fp16_kernel<<<dim3(8192, 3), 256, 0, stream>>>(
        query, key, value, Xq, Xk, Xv, n4);
    transpose_w_kernel<<<dim3(32, 32, 4), bT, 0, stream>>>(
        wq, wk, wv, wo, Wtq, Wtk, Wtv, Wto);
    gemm_qkv_kernel<<<1536, 256, 0, stream>>>(
        Xq, Xk, Xv, Wtq, Wtk, Wtv, bq, bk, bv, Qb, Kb, Vtg);
    attn_kernel<<<512, 512, 0, stream>>>(Qb, Kb, Vtg, Of);
    gemm_out_kernel<<<1024, 256, 0, stream>>>(Of, Wto, bo, (float*)d_out);
}

// Round 13
// 202.052 us; speedup vs baseline: 1.1252x; 1.0483x over previous
//
#include <hip/hip_runtime.h>

// ---------------------------------------------------------------------------
// MultiHeadAttention: B=4, S=2048, D=1024, H=16, dk=64
// R13: QKV GEMM retiled to 128x64 (the out-proj tile shape, measured 716 TF
//      vs 651 for 128x128 at this K): grid 3072 = 12 blocks/CU, 48 KB
//      staging/step, same XCD m-slab decode. All other kernels unchanged
//      from R12 (each at its measured-best configuration).
// ---------------------------------------------------------------------------

typedef _Float16 fp16;
typedef fp16  fp16x8 __attribute__((ext_vector_type(8)));
typedef fp16  fp16x4 __attribute__((ext_vector_type(4)));
typedef __fp16 h16x2 __attribute__((ext_vector_type(2)));
typedef float f32x4  __attribute__((ext_vector_type(4)));

#define NROWS 8192     // B*S
#define DM    1024
#define SEQ   2048
#define DK    64
#define LOG2E 1.44269504088896340736f
#define QSCALE (0.125f * LOG2E)

__device__ __forceinline__ f32x4 mfma16x16(fp16x8 a, fp16x8 b, f32x4 c) {
    return __builtin_amdgcn_mfma_f32_16x16x32_f16(a, b, c, 0, 0, 0);
}

__device__ __forceinline__ void gload16(const void* g, void* l) {
    __builtin_amdgcn_global_load_lds(
        (const __attribute__((address_space(1))) void*)g,
        (__attribute__((address_space(3))) void*)l, 16, 0, 0);
}

// pack 4 f32 -> fp16x4 with v_cvt_pkrtz (2 instructions)
__device__ __forceinline__ fp16x4 pack4(float a, float b, float c, float d) {
    h16x2 r0 = __builtin_amdgcn_cvt_pkrtz(a, b);
    h16x2 r1 = __builtin_amdgcn_cvt_pkrtz(c, d);
    fp16x4 v;
    v[0] = (fp16)r0[0]; v[1] = (fp16)r0[1];
    v[2] = (fp16)r1[0]; v[3] = (fp16)r1[1];
    return v;
}

// ---- fp32 -> fp16 cast, z-batched over 3 tensors -------------------------
__global__ __launch_bounds__(256) void cast_fp16_kernel(
    const float* __restrict__ x0, const float* __restrict__ x1,
    const float* __restrict__ x2,
    fp16* __restrict__ y0, fp16* __restrict__ y1, fp16* __restrict__ y2,
    int n4) {
    const int z = blockIdx.y;
    const float* x = (z == 0) ? x0 : (z == 1) ? x1 : x2;
    fp16*       y = (z == 0) ? y0 : (z == 1) ? y1 : y2;
    int i = blockIdx.x * 256 + threadIdx.x;
    if (i >= n4) return;
    const float4 v = ((const float4*)x)[i];
    ((fp16x4*)y)[i] = pack4(v.x, v.y, v.z, v.w);
}

// ---- transpose 1024x1024 fp32 W[k][n] -> fp16 T[n][k], z-batched x4 ------
__global__ __launch_bounds__(256) void transpose_w_kernel(
    const float* __restrict__ w0, const float* __restrict__ w1,
    const float* __restrict__ w2, const float* __restrict__ w3,
    fp16* __restrict__ t0, fp16* __restrict__ t1,
    fp16* __restrict__ t2, fp16* __restrict__ t3) {
    const int z = blockIdx.z;
    const float* W = (z == 0) ? w0 : (z == 1) ? w1 : (z == 2) ? w2 : w3;
    fp16*       T = (z == 0) ? t0 : (z == 1) ? t1 : (z == 2) ? t2 : t3;
    __shared__ float tile[32][33];
    const int tx = threadIdx.x, ty = threadIdx.y;
    const int bx = blockIdx.x * 32, by = blockIdx.y * 32;
#pragma unroll
    for (int j = 0; j < 4; ++j)
        tile[ty + 8 * j][tx] = W[(size_t)(by + ty + 8 * j) * DM + bx + tx];
    __syncthreads();
#pragma unroll
    for (int j = 0; j < 4; ++j)
        T[(size_t)(bx + ty + 8 * j) * DM + by + tx] = (fp16)tile[tx][ty + 8 * j];
}

// ---- QKV projection GEMM: 128x64 tile (out-proj shape), XCD decode -------
// Grid: 3072 1D. Decode: xcd = i&7 owns m-slabs [xcd*8, xcd*8+8) for all
// n (16 tiles of 64) and z. 12 blocks/CU. z 0: Q (scale), 1: K, 2: V^T out.
__global__ __launch_bounds__(256) void gemm_qkv_kernel(
    const fp16* __restrict__ Xq, const fp16* __restrict__ Xk,
    const fp16* __restrict__ Xv,
    const fp16* __restrict__ Wq, const fp16* __restrict__ Wk,
    const fp16* __restrict__ Wv,
    const float* __restrict__ bq, const float* __restrict__ bk,
    const float* __restrict__ bv,
    fp16* __restrict__ Qb, fp16* __restrict__ Kb, fp16* __restrict__ Vtg) {
    const int i = blockIdx.x;
    const int xcd = i & 7, r = i >> 3;           // r in [0,384)
    const int z = r >> 7, rr = r & 127;
    const int m0 = (xcd * 8 + (rr >> 4)) * 128;  // m-slab, XCD-local
    const int n0 = (rr & 15) * 64;

    const fp16* __restrict__ A = (z == 0) ? Xq : (z == 1) ? Xk : Xv;
    const fp16* __restrict__ B = (z == 0) ? Wq : (z == 1) ? Wk : Wv;
    const float* __restrict__ bias = (z == 0) ? bq : (z == 1) ? bk : bv;
    fp16* __restrict__ outp = (z == 0) ? Qb : (z == 1) ? Kb : Vtg;
    const float oscale = (z == 0) ? QSCALE : 1.0f;

    const int tid = threadIdx.x;
    const int lane = tid & 63;
    const int w = tid >> 6;
    const int wr = w >> 1, wc = w & 1;
    const int li = lane & 15, lg = lane >> 4;
    const int lrow = lane >> 3;
    const int lch  = (lane & 7) ^ lrow;          // pre-swizzled source chunk

    __shared__ fp16 At[128 * 64];
    __shared__ fp16 Bt[64 * 64];

    f32x4 acc[4][2] = {};

    for (int k0 = 0; k0 < DM; k0 += 64) {
        __syncthreads();
#pragma unroll
        for (int it = 0; it < 4; ++it) {
            int R = (w * 4 + it) * 8 + lrow;
            gload16(&A[(size_t)(m0 + R) * DM + k0 + lch * 8], &At[(w * 4 + it) * 512]);
            if (it < 2) {
                int Rb = (w * 2 + it) * 8 + lrow;
                gload16(&B[(size_t)(n0 + Rb) * DM + k0 + lch * 8], &Bt[(w * 2 + it) * 512]);
            }
        }
        __syncthreads();
        fp16x8 af[4][2], bfr[2][2];
#pragma unroll
        for (int mf = 0; mf < 4; ++mf)
#pragma unroll
            for (int ks = 0; ks < 2; ++ks)
                af[mf][ks] = *(const fp16x8*)&At[(wr * 64 + mf * 16 + li) * 64 +
                                                 (((ks * 4 + lg) ^ (li & 7)) * 8)];
#pragma unroll
        for (int nf = 0; nf < 2; ++nf)
#pragma unroll
            for (int ks = 0; ks < 2; ++ks)
                bfr[nf][ks] = *(const fp16x8*)&Bt[(wc * 32 + nf * 16 + li) * 64 +
                                                  (((ks * 4 + lg) ^ (li & 7)) * 8)];
#pragma unroll
        for (int ks = 0; ks < 2; ++ks)
#pragma unroll
            for (int mf = 0; mf < 4; ++mf)
#pragma unroll
                for (int nf = 0; nf < 2; ++nf)
                    acc[mf][nf] = mfma16x16(af[mf][ks], bfr[nf][ks], acc[mf][nf]);
    }
#pragma unroll
    for (int nf = 0; nf < 2; ++nf) {
        int col = n0 + wc * 32 + nf * 16 + li;
        float bv_ = bias[col];
        if (z == 2) {           // V^T layout [b*1024 + col][s]
#pragma unroll
            for (int mf = 0; mf < 4; ++mf) {
                int rowb = m0 + wr * 64 + mf * 16 + lg * 4;
                fp16x4 pk;
#pragma unroll
                for (int r2 = 0; r2 < 4; ++r2)
                    pk[r2] = (fp16)(acc[mf][nf][r2] + bv_);
                size_t o = ((size_t)(rowb >> 11) * 1024 + col) * SEQ + (rowb & 2047);
                *(fp16x4*)&outp[o] = pk;
            }
        } else {
#pragma unroll
            for (int mf = 0; mf < 4; ++mf)
#pragma unroll
                for (int r2 = 0; r2 < 4; ++r2) {
                    int row = m0 + wr * 64 + mf * 16 + lg * 4 + r2;
                    outp[(size_t)row * DM + col] = (fp16)((acc[mf][nf][r2] + bv_) * oscale);
                }
        }
    }
}

// ---- Out-projection GEMM: fp16 A/B, 128x64 tile, XCD-aware decode --------
__global__ __launch_bounds__(256) void gemm_out_kernel(
    const fp16* __restrict__ A, const fp16* __restrict__ B,
    const float* __restrict__ bias, float* __restrict__ outp) {
    const int i = blockIdx.x;
    const int xcd = i & 7, r = i >> 3;           // r in [0,128)
    const int m0 = (xcd * 8 + (r >> 4)) * 128;
    const int n0 = (r & 15) * 64;

    const int tid = threadIdx.x;
    const int lane = tid & 63;
    const int w = tid >> 6;
    const int wr = w >> 1, wc = w & 1;
    const int li = lane & 15, lg = lane >> 4;
    const int lrow = lane >> 3;
    const int lch  = (lane & 7) ^ lrow;

    __shared__ fp16 At[128 * 64];
    __shared__ fp16 Bt[64 * 64];

    f32x4 acc[4][2] = {};

    for (int k0 = 0; k0 < DM; k0 += 64) {
        __syncthreads();
#pragma unroll
        for (int it = 0; it < 4; ++it) {
            int R = (w * 4 + it) * 8 + lrow;
            gload16(&A[(size_t)(m0 + R) * DM + k0 + lch * 8], &At[(w * 4 + it) * 512]);
            if (it < 2) {
                int Rb = (w * 2 + it) * 8 + lrow;
                gload16(&B[(size_t)(n0 + Rb) * DM + k0 + lch * 8], &Bt[(w * 2 + it) * 512]);
            }
        }
        __syncthreads();
        fp16x8 af[4][2], bfr[2][2];
#pragma unroll
        for (int mf = 0; mf < 4; ++mf)
#pragma unroll
            for (int ks = 0; ks < 2; ++ks)
                af[mf][ks] = *(const fp16x8*)&At[(wr * 64 + mf * 16 + li) * 64 +
                                                 (((ks * 4 + lg) ^ (li & 7)) * 8)];
#pragma unroll
        for (int nf = 0; nf < 2; ++nf)
#pragma unroll
            for (int ks = 0; ks < 2; ++ks)
                bfr[nf][ks] = *(const fp16x8*)&Bt[(wc * 32 + nf * 16 + li) * 64 +
                                                  (((ks * 4 + lg) ^ (li & 7)) * 8)];
#pragma unroll
        for (int ks = 0; ks < 2; ++ks)
#pragma unroll
            for (int mf = 0; mf < 4; ++mf)
#pragma unroll
                for (int nf = 0; nf < 2; ++nf)
                    acc[mf][nf] = mfma16x16(af[mf][ks], bfr[nf][ks], acc[mf][nf]);
    }
#pragma unroll
    for (int nf = 0; nf < 2; ++nf) {
        int col = n0 + wc * 32 + nf * 16 + li;
        float bv_ = bias[col];
#pragma unroll
        for (int mf = 0; mf < 4; ++mf)
#pragma unroll
            for (int r2 = 0; r2 < 4; ++r2) {
                int row = m0 + wr * 64 + mf * 16 + lg * 4 + r2;
                outp[(size_t)row * DM + col] = acc[mf][nf][r2] + bv_;
            }
    }
}

// ---- Flash attention: swapped QK^T, 8 waves, no-max softmax, K/V LDS dbuf,
//      ONE barrier per KV tile (loads issued a full compute phase early).
__global__ __launch_bounds__(512) void attn_kernel(
    const fp16* __restrict__ Qb, const fp16* __restrict__ Kb,
    const fp16* __restrict__ Vtg, fp16* __restrict__ Of) {
    const int tid = threadIdx.x;
    const int lane = tid & 63;
    const int w = tid >> 6;                  // 0..7
    const int li = lane & 15, lg = lane >> 4;

    int L = blockIdx.x;
    L = (L & 7) * 64 + (L >> 3);             // bijective XCD swizzle (512 = 8*64)
    const int qt = L & 7, bh = L >> 3;
    const int b = bh >> 4, h = bh & 15;
    const size_t rowQ = (size_t)b * SEQ + (size_t)qt * 256;
    const int c0 = h * DK;

    __shared__ fp16 Kt[2][64 * 64];     // [kv][d], chunk-swizzled
    __shared__ fp16 Vt[2][64 * 64];     // [d][kv], chunk-swizzled
    __shared__ fp16 Pl[8][32 * 64];     // per-wave P [q][kv], chunk-swizzled

    fp16x8 qf[2][2];
#pragma unroll
    for (int mf = 0; mf < 2; ++mf)
#pragma unroll
        for (int ks = 0; ks < 2; ++ks)
            qf[mf][ks] = *(const fp16x8*)&Qb[(rowQ + w * 32 + mf * 16 + li) * DM +
                                             c0 + ks * 32 + lg * 8];

    fp16x8 ones;
#pragma unroll
    for (int j = 0; j < 8; ++j) ones[j] = (fp16)1.0f;

    f32x4 oacc[2][4] = {};
    f32x4 lacc[2] = {};

    const int sr = tid >> 3, sc = tid & 7;
    const int ssl = sc ^ (sr & 7);
    fp16x8 rk, rv;
    rk = *(const fp16x8*)&Kb[((size_t)b * SEQ + sr) * DM + c0 + sc * 8];
    rv = *(const fp16x8*)&Vtg[((size_t)bh * 64 + sr) * SEQ + sc * 8];
    *(fp16x8*)&Kt[0][sr * 64 + ssl * 8] = rk;
    *(fp16x8*)&Vt[0][sr * 64 + ssl * 8] = rv;
    __syncthreads();

    for (int kt = 0; kt < SEQ / 64; ++kt) {
        const int cur = kt & 1;
        const bool more = (kt + 1 < SEQ / 64);
        if (more) {                      // loads overlap the whole compute phase
            rk = *(const fp16x8*)&Kb[((size_t)b * SEQ + (kt + 1) * 64 + sr) * DM + c0 + sc * 8];
            rv = *(const fp16x8*)&Vtg[((size_t)bh * 64 + sr) * SEQ + (kt + 1) * 64 + sc * 8];
        }

        // S^T = K Q^T : lane holds q=li, kv=nf*16+lg*4+r
        f32x4 s[4][2] = {};
        __builtin_amdgcn_s_setprio(1);
#pragma unroll
        for (int nf = 0; nf < 4; ++nf)
#pragma unroll
            for (int ks = 0; ks < 2; ++ks) {
                fp16x8 kf = *(const fp16x8*)&Kt[cur][(nf * 16 + li) * 64 +
                                                     (((ks * 4 + lg) ^ (li & 7)) * 8)];
#pragma unroll
                for (int mf = 0; mf < 2; ++mf)
                    s[nf][mf] = mfma16x16(kf, qf[mf][ks], s[nf][mf]);
            }
        __builtin_amdgcn_s_setprio(0);

        // p = exp2(s) -> per-wave LDS (pkrtz pack, swizzled)
#pragma unroll
        for (int mf = 0; mf < 2; ++mf) {
            int row = mf * 16 + li;
#pragma unroll
            for (int nf = 0; nf < 4; ++nf) {
                fp16x4 pk = pack4(
                    __builtin_amdgcn_exp2f(s[nf][mf][0]),
                    __builtin_amdgcn_exp2f(s[nf][mf][1]),
                    __builtin_amdgcn_exp2f(s[nf][mf][2]),
                    __builtin_amdgcn_exp2f(s[nf][mf][3]));
                int sl = (nf * 2 + (lg >> 1)) ^ (li & 7);
                *(fp16x4*)&Pl[w][row * 64 + sl * 8 + (lg & 1) * 4] = pk;
            }
        }

        // O += P V ; l += P 1
        __builtin_amdgcn_s_setprio(1);
#pragma unroll
        for (int ks = 0; ks < 2; ++ks) {
            fp16x8 pf[2];
#pragma unroll
            for (int mf = 0; mf < 2; ++mf) {
                pf[mf] = *(const fp16x8*)&Pl[w][(mf * 16 + li) * 64 +
                                                (((ks * 4 + lg) ^ (li & 7)) * 8)];
                lacc[mf] = mfma16x16(pf[mf], ones, lacc[mf]);
            }
#pragma unroll
            for (int nf = 0; nf < 4; ++nf) {
                fp16x8 vf = *(const fp16x8*)&Vt[cur][(nf * 16 + li) * 64 +
                                                     (((ks * 4 + lg) ^ (li & 7)) * 8)];
#pragma unroll
                for (int mf = 0; mf < 2; ++mf)
                    oacc[mf][nf] = mfma16x16(pf[mf], vf, oacc[mf][nf]);
            }
        }
        __builtin_amdgcn_s_setprio(0);

        if (more) {                      // stage tile kt+1 into the other buffer
            *(fp16x8*)&Kt[cur ^ 1][sr * 64 + ssl * 8] = rk;
            *(fp16x8*)&Vt[cur ^ 1][sr * 64 + ssl * 8] = rv;
            __syncthreads();             // one barrier per tile
        }
    }

    // epilogue: O /= l (lacc in oacc row layout), write fp16
#pragma unroll
    for (int mf = 0; mf < 2; ++mf) {
#pragma unroll
        for (int r = 0; r < 4; ++r) {
            float linv = 1.0f / lacc[mf][r];
            size_t row = rowQ + w * 32 + mf * 16 + lg * 4 + r;
#pragma unroll
            for (int nf = 0; nf < 4; ++nf) {
                int col = c0 + nf * 16 + li;
                Of[row * DM + col] = (fp16)(oacc[mf][nf][r] * linv);
            }
        }
    }
}

// ---------------------------------------------------------------------------
extern "C" void kernel_launch(void* const* d_in, const int* in_sizes, int n_in,
                              void* d_out, int out_size, void* d_ws, size_t ws_size,
                              hipStream_t stream) {
    const float* query = (const float*)d_in[0];
    const float* key   = (const float*)d_in[1];
    const float* value = (const float*)d_in[2];
    const float* wq    = (const float*)d_in[3];
    const float* bq    = (const float*)d_in[4];
    const float* wk    = (const float*)d_in[5];
    const float* bk    = (const float*)d_in[6];
    const float* wv    = (const float*)d_in[7];
    const float* bv    = (const float*)d_in[8];
    const float* wo    = (const float*)d_in[9];
    const float* bo    = (const float*)d_in[10];

    char* ws = (char*)d_ws;
    const size_t SZX = (size_t)NROWS * DM * 2;   // 16 MB (fp16)
    const size_t SZW = (size_t)DM * DM * 2;      //  2 MB (fp16)
    fp16* Xq  = (fp16*)(ws);
    fp16* Xk  = (fp16*)(ws + SZX);
    fp16* Xv  = (fp16*)(ws + 2 * SZX);
    fp16* Wtq = (fp16*)(ws + 3 * SZX);
    fp16* Wtk = (fp16*)(ws + 3 * SZX + SZW);
    fp16* Wtv = (fp16*)(ws + 3 * SZX + 2 * SZW);
    fp16* Wto = (fp16*)(ws + 3 * SZX + 3 * SZW);
    fp16* Qb  = (fp16*)(ws + 3 * SZX + 4 * SZW);
    fp16* Kb  = (fp16*)(ws + 4 * SZX + 4 * SZW);
    fp16* Vtg = (fp16*)(ws + 5 * SZX + 4 * SZW); // V^T [b*1024+h*64+d][s]
    fp16* Of  = Xq;                              // Xq dead after QKV GEMMs

    const int n4 = NROWS * DM / 4;
    const dim3 bT(32, 8);

    cast_fp16_kernel<<<dim3(8192, 3), 256, 0, stream>>>(
        query, key, value, Xq, Xk, Xv, n4);
    transpose_w_kernel<<<dim3(32, 32, 4), bT, 0, stream>>>(
        wq, wk, wv, wo, Wtq, Wtk, Wtv, Wto);
    gemm_qkv_kernel<<<3072, 256, 0, stream>>>(
        Xq, Xk, Xv, Wtq, Wtk, Wtv, bq, bk, bv, Qb, Kb, Vtg);
    attn_kernel<<<512, 512, 0, stream>>>(Qb, Kb, Vtg, Of);
    gemm_out_kernel<<<1024, 256, 0, stream>>>(Of, Wto, bo, (float*)d_out);
}